// Round 8
// baseline (69.421 us; speedup 1.0000x reference)
//
#include <hip/hip_runtime.h>

#define B_ 512
#define M_ 32
#define D_ 2048

typedef float fvec4 __attribute__((ext_vector_type(4)));

// One block per batch; 1024 threads = 512 float4-positions x 2 row-halves.
// Thread owns ONE float4 position across 16 rows: its 3 w-float4s are loaded
// once and reused for all 16 rows (16x less w traffic than row-major ownership).
// Single __syncthreads; phase B is wave-parallel and redundant per wave.
__global__ __launch_bounds__(1024, 4) void ephaptic_fused(const float* __restrict__ x,
                                                          const float* __restrict__ w,
                                                          float* __restrict__ out) {
    const int b = blockIdx.x;
    const int tid = threadIdx.x;
    const int wv = tid >> 6;        // wave 0..15
    const int lane = tid & 63;
    const int h = wv >> 3;          // half: rows h*16 .. h*16+15
    const int p = tid & 511;        // float4 position within the row

    __shared__ float sF[M_], sL[M_];     // first/last element per row
    __shared__ float swv[16][16];        // [wave][row-in-half] wave-partial row sums

    const float* xb = x + (size_t)b * M_ * D_;
    float* ob = out + (size_t)b * M_ * D_;

    // w for this position (L1-resident, 48 B/thread TOTAL)
    const fvec4* wf = (const fvec4*)w;
    const fvec4 w0 = wf[p * 3 + 0];
    const fvec4 w1 = wf[p * 3 + 1];
    const fvec4 w2 = wf[p * 3 + 2];

    // ---- Phase A: load x[row][p] for 16 rows; per-row horizontal partial sums
    fvec4 v[16];
    float s[16];
#pragma unroll
    for (int r = 0; r < 16; ++r) {
        v[r] = ((const fvec4*)(xb + (size_t)(h * 16 + r) * D_))[p];
        s[r] = (v[r].x + v[r].y) + (v[r].z + v[r].w);
    }
    // full-wave butterfly: every lane ends with the wave-total for each row
#pragma unroll
    for (int off = 32; off > 0; off >>= 1) {
#pragma unroll
        for (int r = 0; r < 16; ++r) s[r] += __shfl_xor(s[r], off, 64);
    }
    if (lane == 0) {
#pragma unroll
        for (int r = 0; r < 16; ++r) swv[wv][r] = s[r];
    }
    if (p == 0) {          // tid 0 (rows 0..15) and tid 512 (rows 16..31)
#pragma unroll
        for (int r = 0; r < 16; ++r) sF[h * 16 + r] = v[r].x;
    }
    if (p == 511) {        // x[row][2047]
#pragma unroll
        for (int r = 0; r < 16; ++r) sL[h * 16 + r] = v[r].w;
    }
    __syncthreads();   // the only block barrier

    // ---- Phase B (redundant per wave): row totals + decay matvec for this half's rows
    // lane j (j = lane&31) prepares tap sums for row j
    float a0, a1, a2;
    {
        const int j = lane & 31;
        const int jh = j >> 4;
        float T = 0.f;
#pragma unroll
        for (int k = 0; k < 8; ++k) T += swv[jh * 8 + k][j & 15];
        a1 = T;            // tap k=1 (offset 0)
        a0 = T - sL[j];    // tap k=0 (offset -1): drop last element
        a2 = T - sF[j];    // tap k=2 (offset +1): drop first element
    }
    // 4 lanes per row: lane = 4*ri + q, partial over j = q, q+4, ..., q+28
    const int ri = lane >> 2;
    const int q = lane & 3;
    const int i = h * 16 + ri;
    float r0 = 0.f, r1 = 0.f, r2 = 0.f;
#pragma unroll
    for (int it = 0; it < 8; ++it) {
        const int j = q + 4 * it;
        const float d = (j == i) ? 0.f : __expf(-0.5f * fabsf((float)(i - j)));
        r0 += d * __shfl(a0, j, 64);
        r1 += d * __shfl(a1, j, 64);
        r2 += d * __shfl(a2, j, 64);
    }
    // reduce across the 4 lanes of each row group
    r0 += __shfl_xor(r0, 1, 64); r0 += __shfl_xor(r0, 2, 64);
    r1 += __shfl_xor(r1, 1, 64); r1 += __shfl_xor(r1, 2, 64);
    r2 += __shfl_xor(r2, 1, 64); r2 += __shfl_xor(r2, 2, 64);
    const float sc = 0.1f / (float)D_;
    r0 *= sc; r1 *= sc; r2 *= sc;   // lane 4*ri now holds row ri's coefs

    // ---- Phase C: out[row][p] = x + c0*w(:,0) + c1*w(:,1) + c2*w(:,2)
#pragma unroll
    for (int r = 0; r < 16; ++r) {
        const float c0 = __shfl(r0, 4 * r, 64);   // broadcast from lane 4r
        const float c1 = __shfl(r1, 4 * r, 64);
        const float c2 = __shfl(r2, 4 * r, 64);
        fvec4 o;
        o.x = v[r].x + c0 * w0.x + c1 * w0.y + c2 * w0.z;
        o.y = v[r].y + c0 * w0.w + c1 * w1.x + c2 * w1.y;
        o.z = v[r].z + c0 * w1.z + c1 * w1.w + c2 * w2.x;
        o.w = v[r].w + c0 * w2.y + c1 * w2.z + c2 * w2.w;
        // nontemporal: out is never re-read; keep L3 free so x stays resident
        __builtin_nontemporal_store(o, ((fvec4*)(ob + (size_t)(h * 16 + r) * D_)) + p);
    }
}

extern "C" void kernel_launch(void* const* d_in, const int* in_sizes, int n_in,
                              void* d_out, int out_size, void* d_ws, size_t ws_size,
                              hipStream_t stream) {
    const float* x = (const float*)d_in[0];
    const float* w = (const float*)d_in[1];
    float* out = (float*)d_out;
    ephaptic_fused<<<B_, 1024, 0, stream>>>(x, w, out);
}

// Round 9
// 55.665 us; speedup vs baseline: 1.2471x; 1.2471x over previous
//
#include <hip/hip_runtime.h>
#include <stdint.h>

#define B_ 512
#define M_ 32
#define D_ 2048

typedef float fvec4 __attribute__((ext_vector_type(4)));

// pack two f32 -> one u32 of bf16 (RNE, hardware): bits[15:0]=lo, bits[31:16]=hi
static __device__ __forceinline__ uint32_t pk_bf16(float lo, float hi) {
    uint32_t r;
    asm("v_cvt_pk_bf16_f32 %0, %1, %2" : "=v"(r) : "v"(lo), "v"(hi));
    return r;
}
static __device__ __forceinline__ float bf_lo(uint32_t u) { return __uint_as_float(u << 16); }
static __device__ __forceinline__ float bf_hi(uint32_t u) { return __uint_as_float(u & 0xFFFF0000u); }

// One block per batch. 1024 threads = 32 rows x 32 threads/row (round-2 structure).
// Each thread holds its 16 float4s of x ACROSS the barrier as 32 u32 of packed
// bf16 (32 VGPRs) -- fits the compiler's 64-VGPR/8-wave budget, so no load
// sinking (rounds 2/5) and no scratch spill (round 8). True single HBM pass:
// coefs are computed from exact f32 sums; only the "+x" output term is bf16.
__global__ __launch_bounds__(1024) void ephaptic_fused(const float* __restrict__ x,
                                                       const float* __restrict__ w,
                                                       float* __restrict__ out) {
    const int b = blockIdx.x;
    const int tid = threadIdx.x;
    const int m = tid >> 5;   // row 0..31
    const int t = tid & 31;   // position group within row

    __shared__ float sT[M_], sF[M_], sL[M_];
    __shared__ fvec4 sC[M_];

    const size_t rowbase = ((size_t)b * M_ + m) * (size_t)D_;
    const fvec4* row = (const fvec4*)(x + rowbase);

    // Phase A: load row slice, accumulate exact f32 row sum, pack to bf16.
    uint32_t u[32];
    float sum = 0.f;
    float first = 0.f, last = 0.f;
#pragma unroll
    for (int q = 0; q < 16; ++q) {
        const fvec4 v = row[t + 32 * q];
        sum += (v.x + v.y) + (v.z + v.w);
        if (q == 0)  first = v.x;    // x[b][m][0]    (used by lane t==0)
        if (q == 15) last  = v.w;    // x[b][m][2047] (used by lane t==31)
        u[2 * q]     = pk_bf16(v.x, v.y);
        u[2 * q + 1] = pk_bf16(v.z, v.w);
    }
    // butterfly within the 32-lane row group
#pragma unroll
    for (int off = 16; off > 0; off >>= 1)
        sum += __shfl_xor(sum, off, 64);
    if (t == 0)  { sT[m] = sum; sF[m] = first; }
    if (t == 31) { sL[m] = last; }
    __syncthreads();

    // Phase B: 32x32 decay matvec -> per-row coefficients (one wave; ~1% of time).
    if (tid < M_) {
        const int i = tid;
        float r0 = 0.f, r1 = 0.f, r2 = 0.f;
        for (int j = 0; j < M_; ++j) {
            if (j == i) continue;
            const float dij = __expf(-0.5f * fabsf((float)(i - j)));
            const float T = sT[j];
            r0 += dij * (T - sL[j]);   // tap k=0: drop last element
            r1 += dij * T;             // tap k=1
            r2 += dij * (T - sF[j]);   // tap k=2: drop first element
        }
        const float s = 0.1f / (float)D_;
        sC[i] = (fvec4){r0 * s, r1 * s, r2 * s, 0.f};
    }
    __syncthreads();

    // Phase C: out = bf16(x) + coef . w[c,:]; w is [D,3] row-major.
    const fvec4 co = sC[m];
    const fvec4* wf = (const fvec4*)w;
    fvec4* orow = (fvec4*)(out + rowbase);
#pragma unroll
    for (int q = 0; q < 16; ++q) {
        const int c4 = t + 32 * q;
        const fvec4 w0 = wf[c4 * 3 + 0];
        const fvec4 w1 = wf[c4 * 3 + 1];
        const fvec4 w2 = wf[c4 * 3 + 2];
        fvec4 o;
        o.x = bf_lo(u[2 * q])     + co.x * w0.x + co.y * w0.y + co.z * w0.z;
        o.y = bf_hi(u[2 * q])     + co.x * w0.w + co.y * w1.x + co.z * w1.y;
        o.z = bf_lo(u[2 * q + 1]) + co.x * w1.z + co.y * w1.w + co.z * w2.x;
        o.w = bf_hi(u[2 * q + 1]) + co.x * w2.y + co.y * w2.z + co.z * w2.w;
        // nontemporal: out is never re-read; keep L3 free so x stays resident
        __builtin_nontemporal_store(o, orow + c4);
    }
}

extern "C" void kernel_launch(void* const* d_in, const int* in_sizes, int n_in,
                              void* d_out, int out_size, void* d_ws, size_t ws_size,
                              hipStream_t stream) {
    const float* x = (const float*)d_in[0];
    const float* w = (const float*)d_in[1];
    float* out = (float*)d_out;
    ephaptic_fused<<<B_, 1024, 0, stream>>>(x, w, out);
}